// Round 18
// baseline (451.024 us; speedup 1.0000x reference)
//
#include <hip/hip_runtime.h>
#include <math.h>

#define NREG  8
#define HDIM  128
#define NDEPTH 3
#define TP    64      // points per workgroup tile (= lanes per wave)
#define W0F   30.0f

// ---------------- routing helpers ----------------

__device__ __forceinline__ int region_of(float X, float Y, float Z, bool* valid) {
    *valid = (X >= 0.f) & (X <= 1.f) & (Y >= 0.f) & (Y <= 1.f) & (Z >= 0.f) & (Z <= 1.f);
    // box r = i*4 + j*2 + k ; ties at 0.5 belong to the lower box (argmax picks first)
    int i = (X > 0.5f) ? 1 : 0;
    int j = (Y > 0.5f) ? 1 : 0;
    int k = (Z > 0.5f) ? 1 : 0;
    return i * 4 + j * 2 + k;
}

// ws int layout: [0..7] counts, [8..16] offsets(exclusive, +total), [20..27] cursors
__global__ __launch_bounds__(256) void k_count(const float* __restrict__ x, int n,
                                               int* __restrict__ ws) {
    __shared__ int h[NREG];
    if (threadIdx.x < NREG) h[threadIdx.x] = 0;
    __syncthreads();
    int i = blockIdx.x * 256 + threadIdx.x;
    if (i < n) {
        float X = x[3*i], Y = x[3*i+1], Z = x[3*i+2];
        bool valid;
        int r = region_of(X, Y, Z, &valid);
        if (valid) atomicAdd(&h[r], 1);
    }
    __syncthreads();
    if (threadIdx.x < NREG) atomicAdd(&ws[threadIdx.x], h[threadIdx.x]);
}

__global__ void k_prefix(int* __restrict__ ws) {
    if (threadIdx.x == 0) {
        int acc = 0;
        for (int r = 0; r < NREG; ++r) {
            ws[8 + r] = acc;      // offsets
            ws[20 + r] = acc;     // cursors
            acc += ws[r];
        }
        ws[8 + NREG] = acc;
    }
}

// Block-aggregated scatter: LDS-rank within block, ONE global atomic per
// (block, region) chunk reservation, then direct stores.
__global__ __launch_bounds__(256) void k_scatter(const float* __restrict__ x, int n,
                                                 int* __restrict__ ws,
                                                 int* __restrict__ idx,
                                                 float* __restrict__ out) {
    __shared__ int hist[NREG];
    __shared__ int base[NREG];
    const int tid = threadIdx.x;
    if (tid < NREG) hist[tid] = 0;
    __syncthreads();
    int i = blockIdx.x * 256 + tid;
    int r = 0, rank = 0;
    bool valid = false;
    if (i < n) {
        float X = x[3*i], Y = x[3*i+1], Z = x[3*i+2];
        r = region_of(X, Y, Z, &valid);
        if (valid) rank = atomicAdd(&hist[r], 1);   // within-block rank
        else out[i] = 0.0f;   // points outside all boxes stay zero
    }
    __syncthreads();
    if (tid < NREG) {
        int c = hist[tid];
        base[tid] = c ? atomicAdd(&ws[20 + tid], c) : 0;
    }
    __syncthreads();
    if (valid) idx[base[r] + rank] = i;
}

// ---------------- fused per-region SIREN MLP ----------------
// FORCED-VMEM + PREFETCH build. r16 post-mortem: readfirstlane-uniform
// weight addresses got scalarized back to s_load (identical VGPR=48
// fingerprint to r15) -- the VMEM experiment never ran. Here the weight
// base derives from DIVERGENT wv (tid>>6, no readfirstlane) so hipcc must
// emit global_load_dwordx4 (per-lane-equal addrs coalesce to one L1 req +
// broadcast), and the VMEM pipe supports deep counted vmcnt pipelining.
// 1024 threads = 16 waves x 8ch/wave; TP=64; hA 32KB; 2 blocks/CU
// (thread-capped) = 32 waves/CU = 8 waves/SIMD. Explicit 1-j-ahead
// prefetch (weights+act), static rotation, acc[8]+4 float4 in flight
// ~= 50-60 VGPR, under the 64-VGPR occupancy cliff (m69).
// Same per-point arithmetic order as r15/r16 -> absmax 0.04919434 exact.

__global__ __launch_bounds__(1024) void k_mlp(
    const float* __restrict__ x,
    const float* __restrict__ W_in,  const float* __restrict__ b_in,
    const float* __restrict__ W_h,   const float* __restrict__ b_h,
    const float* __restrict__ W_out, const float* __restrict__ b_out,
    const float* __restrict__ scale, const float* __restrict__ boxes,
    const int* __restrict__ offsets, const int* __restrict__ idx,
    float* __restrict__ out)
{
    __shared__ float hA[HDIM][TP];    // 32 KB [channel][point]
    __shared__ float part[16][TP];    // 4 KB

    const int tid  = threadIdx.x;
    const int wv   = tid >> 6;      // wave id 0..15 -> 8-channel chunk (DIVERGENT on purpose)
    const int lane = tid & 63;      // point within tile
    const int k0   = wv << 3;       // channel base; NOT readfirstlane'd -> weight loads stay VMEM

    // map flat block id -> (region, tile)
    int r = -1, base = 0, cnt = 0;
    {
        int bid = blockIdx.x, acc0 = 0;
        for (int rr = 0; rr < NREG; ++rr) {
            int o0 = offsets[rr], o1 = offsets[rr + 1];
            int c = o1 - o0;
            int t = (c + TP - 1) / TP;
            if (bid < acc0 + t) {
                int tile = bid - acc0;
                r = rr; base = o0 + tile * TP; cnt = c - tile * TP;
                break;
            }
            acc0 += t;
        }
    }
    if (r < 0) return;                 // uniform across the block
    if (cnt > TP) cnt = TP;

    // ---- per-lane point & normalized coords ----
    int g = (lane < cnt) ? idx[base + lane] : -1;
    float xn0 = 0.f, xn1 = 0.f, xn2 = 0.f;
    if (g >= 0) {
        float lo0 = boxes[r*6 + 0], hi0 = boxes[r*6 + 1];
        float lo1 = boxes[r*6 + 2], hi1 = boxes[r*6 + 3];
        float lo2 = boxes[r*6 + 4], hi2 = boxes[r*6 + 5];
        xn0 = (2.0f * (x[3*g+0] - lo0) / (hi0 - lo0) - 1.0f) * scale[r*3 + 0];
        xn1 = (2.0f * (x[3*g+1] - lo1) / (hi1 - lo1) - 1.0f) * scale[r*3 + 1];
        xn2 = (2.0f * (x[3*g+2] - lo2) / (hi2 - lo2) - 1.0f) * scale[r*3 + 2];
    }

    // ---- input layer: hA[k][lane] = sin(30*(xn . W_in[:,k] + b_in[k])) ----
    {
        const float* Wr = W_in + r * 3 * HDIM + k0;   // divergent base -> VMEM
        const float* br = b_in + r * HDIM + k0;
        #pragma unroll
        for (int c = 0; c < 8; ++c) {
            float pre = fmaf(xn0, Wr[0*HDIM + c],
                        fmaf(xn1, Wr[1*HDIM + c],
                        fmaf(xn2, Wr[2*HDIM + c], br[c])));
            hA[k0 + c][lane] = sinf(W0F * pre);
        }
    }
    __syncthreads();

    // ---- hidden layers (1-j-ahead prefetch, static rotation) ----
    for (int l = 0; l < NDEPTH; ++l) {
        const float* Wl = W_h + ((size_t)(r * NDEPTH + l)) * HDIM * HDIM + k0;
        const float* bl = b_h + (r * NDEPTH + l) * HDIM + k0;
        float acc[8];
        #pragma unroll
        for (int c = 0; c < 8; ++c) acc[c] = bl[c];   // bias-init

        float4 wc0 = *(const float4*)(Wl);            // j=0 weights (VMEM)
        float4 wc1 = *(const float4*)(Wl + 4);
        float  ac  = hA[0][lane];                     // j=0 activation

        #pragma unroll 2
        for (int j = 0; j < HDIM - 1; ++j) {
            // prefetch j+1 (issued before current FMAs -> covered by them)
            const float* wr = Wl + (size_t)(j + 1) * HDIM;
            float4 wn0 = *(const float4*)(wr);
            float4 wn1 = *(const float4*)(wr + 4);
            float  an  = hA[j + 1][lane];
            // compute j
            acc[0] = fmaf(wc0.x, ac, acc[0]);
            acc[1] = fmaf(wc0.y, ac, acc[1]);
            acc[2] = fmaf(wc0.z, ac, acc[2]);
            acc[3] = fmaf(wc0.w, ac, acc[3]);
            acc[4] = fmaf(wc1.x, ac, acc[4]);
            acc[5] = fmaf(wc1.y, ac, acc[5]);
            acc[6] = fmaf(wc1.z, ac, acc[6]);
            acc[7] = fmaf(wc1.w, ac, acc[7]);
            wc0 = wn0; wc1 = wn1; ac = an;            // rotate (static)
        }
        // last j
        acc[0] = fmaf(wc0.x, ac, acc[0]);
        acc[1] = fmaf(wc0.y, ac, acc[1]);
        acc[2] = fmaf(wc0.z, ac, acc[2]);
        acc[3] = fmaf(wc0.w, ac, acc[3]);
        acc[4] = fmaf(wc1.x, ac, acc[4]);
        acc[5] = fmaf(wc1.y, ac, acc[5]);
        acc[6] = fmaf(wc1.z, ac, acc[6]);
        acc[7] = fmaf(wc1.w, ac, acc[7]);

        // sin in registers, then in-place overwrite of hA
        #pragma unroll
        for (int c = 0; c < 8; ++c) acc[c] = sinf(W0F * acc[c]);
        __syncthreads();   // all waves finished reading hA
        #pragma unroll
        for (int c = 0; c < 8; ++c) hA[k0 + c][lane] = acc[c];
        __syncthreads();   // writes visible before next layer reads
    }

    // ---- output layer: partial dot per 8-ch chunk, reduce via LDS ----
    {
        const float* Wo = W_out + r * HDIM + k0;      // divergent -> VMEM
        float s = 0.f;
        #pragma unroll
        for (int c = 0; c < 8; ++c)
            s = fmaf(Wo[c], hA[k0 + c][lane], s);
        part[wv][lane] = s;
    }
    __syncthreads();
    if (wv == 0) {
        float s = b_out[r];
        #pragma unroll
        for (int w = 0; w < 16; ++w) s += part[w][lane];
        if (g >= 0) out[g] = s;
    }
}

// ---------------- launcher ----------------

extern "C" void kernel_launch(void* const* d_in, const int* in_sizes, int n_in,
                              void* d_out, int out_size, void* d_ws, size_t ws_size,
                              hipStream_t stream) {
    const float* x      = (const float*)d_in[0];
    const float* W_in   = (const float*)d_in[1];
    const float* b_in   = (const float*)d_in[2];
    const float* W_h    = (const float*)d_in[3];
    const float* b_h    = (const float*)d_in[4];
    const float* W_out  = (const float*)d_in[5];
    const float* b_out  = (const float*)d_in[6];
    const float* scale  = (const float*)d_in[7];
    const float* boxes  = (const float*)d_in[8];
    float* out = (float*)d_out;

    int n = in_sizes[0] / 3;
    int* wsi = (int*)d_ws;
    int* idx = (int*)((char*)d_ws + 256);

    hipMemsetAsync(d_ws, 0, 256, stream);

    int nb = (n + 255) / 256;
    hipLaunchKernelGGL(k_count,   dim3(nb), dim3(256), 0, stream, x, n, wsi);
    hipLaunchKernelGGL(k_prefix,  dim3(1),  dim3(64),  0, stream, wsi);
    hipLaunchKernelGGL(k_scatter, dim3(nb), dim3(256), 0, stream, x, n, wsi, idx, out);

    int ntiles = (n + TP - 1) / TP + NREG;
    hipLaunchKernelGGL(k_mlp, dim3(ntiles), dim3(1024), 0, stream,
                       x, W_in, b_in, W_h, b_h, W_out, b_out, scale, boxes,
                       wsi + 8, idx, out);
}

// Round 19
// 134.744 us; speedup vs baseline: 3.3473x; 3.3473x over previous
//
#include <hip/hip_runtime.h>
#include <math.h>

#define NREG  8
#define HDIM  128
#define NDEPTH 3
#define TP    64      // points per workgroup tile (= lanes per wave)
#define W0F   30.0f

// ---------------- routing helpers ----------------

__device__ __forceinline__ int region_of(float X, float Y, float Z, bool* valid) {
    *valid = (X >= 0.f) & (X <= 1.f) & (Y >= 0.f) & (Y <= 1.f) & (Z >= 0.f) & (Z <= 1.f);
    // box r = i*4 + j*2 + k ; ties at 0.5 belong to the lower box (argmax picks first)
    int i = (X > 0.5f) ? 1 : 0;
    int j = (Y > 0.5f) ? 1 : 0;
    int k = (Z > 0.5f) ? 1 : 0;
    return i * 4 + j * 2 + k;
}

// ws int layout: [0..7] counts, [8..16] offsets(exclusive, +total), [20..27] cursors
__global__ __launch_bounds__(256) void k_count(const float* __restrict__ x, int n,
                                               int* __restrict__ ws) {
    __shared__ int h[NREG];
    if (threadIdx.x < NREG) h[threadIdx.x] = 0;
    __syncthreads();
    int i = blockIdx.x * 256 + threadIdx.x;
    if (i < n) {
        float X = x[3*i], Y = x[3*i+1], Z = x[3*i+2];
        bool valid;
        int r = region_of(X, Y, Z, &valid);
        if (valid) atomicAdd(&h[r], 1);
    }
    __syncthreads();
    if (threadIdx.x < NREG) atomicAdd(&ws[threadIdx.x], h[threadIdx.x]);
}

__global__ void k_prefix(int* __restrict__ ws) {
    if (threadIdx.x == 0) {
        int acc = 0;
        for (int r = 0; r < NREG; ++r) {
            ws[8 + r] = acc;      // offsets
            ws[20 + r] = acc;     // cursors
            acc += ws[r];
        }
        ws[8 + NREG] = acc;
    }
}

// Block-aggregated scatter: LDS-rank within block, ONE global atomic per
// (block, region) chunk reservation, then direct stores.
__global__ __launch_bounds__(256) void k_scatter(const float* __restrict__ x, int n,
                                                 int* __restrict__ ws,
                                                 int* __restrict__ idx,
                                                 float* __restrict__ out) {
    __shared__ int hist[NREG];
    __shared__ int base[NREG];
    const int tid = threadIdx.x;
    if (tid < NREG) hist[tid] = 0;
    __syncthreads();
    int i = blockIdx.x * 256 + tid;
    int r = 0, rank = 0;
    bool valid = false;
    if (i < n) {
        float X = x[3*i], Y = x[3*i+1], Z = x[3*i+2];
        r = region_of(X, Y, Z, &valid);
        if (valid) rank = atomicAdd(&hist[r], 1);   // within-block rank
        else out[i] = 0.0f;   // points outside all boxes stay zero
    }
    __syncthreads();
    if (tid < NREG) {
        int c = hist[tid];
        base[tid] = c ? atomicAdd(&ws[20 + tid], c) : 0;
    }
    __syncthreads();
    if (valid) idx[base[r] + rank] = i;
}

// ---------------- fused per-region SIREN MLP ----------------
// r15 structure (512 thr = 8 waves, 16 ch/wave, hA 32KB, 4 blocks/CU,
// weights via wave-uniform s_load_dwordx16) + J-PHASING: the 128-j loop
// is split into 4 x 32-j phases with a block barrier between phases, so
// all 32 resident waves march through a 16KB weight window together.
// Diagnosis (r13/r15/r16/r18): scalar pipe is the makespan -- 4096
// s_load_x16 per CU-layer against a 64KB footprint thrashing the 32KB
// K$ (~28cyc each ~= 116K cyc = measured layer time, VALUBusy 51%).
// Phasing makes the footprint K$-resident -> compulsory misses only.
// One-variable change vs r15; arithmetic order identical (j ascending)
// -> absmax must reproduce 0.04919434 exactly.
// r18 lesson: tid>>6 is wave-uniform -> scalarized; only (tid&63)-
// dependent addresses stay VMEM.

__global__ __launch_bounds__(512) void k_mlp(
    const float* __restrict__ x,
    const float* __restrict__ W_in,  const float* __restrict__ b_in,
    const float* __restrict__ W_h,   const float* __restrict__ b_h,
    const float* __restrict__ W_out, const float* __restrict__ b_out,
    const float* __restrict__ scale, const float* __restrict__ boxes,
    const int* __restrict__ offsets, const int* __restrict__ idx,
    float* __restrict__ out)
{
    __shared__ float hA[HDIM][TP];    // 32 KB [channel][point]
    __shared__ float part[8][TP];     // 2 KB

    const int tid  = threadIdx.x;
    const int wv   = tid >> 6;      // wave id 0..7 -> 16-channel chunk
    const int lane = tid & 63;      // point within tile
    const int k0   = __builtin_amdgcn_readfirstlane(wv << 4);  // SGPR chunk base

    // map flat block id -> (region, tile)
    int r = -1, base = 0, cnt = 0;
    {
        int bid = blockIdx.x, acc0 = 0;
        for (int rr = 0; rr < NREG; ++rr) {
            int o0 = offsets[rr], o1 = offsets[rr + 1];
            int c = o1 - o0;
            int t = (c + TP - 1) / TP;
            if (bid < acc0 + t) {
                int tile = bid - acc0;
                r = rr; base = o0 + tile * TP; cnt = c - tile * TP;
                break;
            }
            acc0 += t;
        }
    }
    if (r < 0) return;                 // uniform across the block
    if (cnt > TP) cnt = TP;

    // ---- per-lane point & normalized coords ----
    int g = (lane < cnt) ? idx[base + lane] : -1;
    float xn0 = 0.f, xn1 = 0.f, xn2 = 0.f;
    if (g >= 0) {
        float lo0 = boxes[r*6 + 0], hi0 = boxes[r*6 + 1];
        float lo1 = boxes[r*6 + 2], hi1 = boxes[r*6 + 3];
        float lo2 = boxes[r*6 + 4], hi2 = boxes[r*6 + 5];
        xn0 = (2.0f * (x[3*g+0] - lo0) / (hi0 - lo0) - 1.0f) * scale[r*3 + 0];
        xn1 = (2.0f * (x[3*g+1] - lo1) / (hi1 - lo1) - 1.0f) * scale[r*3 + 1];
        xn2 = (2.0f * (x[3*g+2] - lo2) / (hi2 - lo2) - 1.0f) * scale[r*3 + 2];
    }

    // ---- input layer: hA[k][lane] = sin(30*(xn . W_in[:,k] + b_in[k])) ----
    {
        const float* Wr = W_in + r * 3 * HDIM + k0;   // uniform base -> s_load
        const float* br = b_in + r * HDIM + k0;
        #pragma unroll
        for (int c = 0; c < 16; ++c) {
            float pre = fmaf(xn0, Wr[0*HDIM + c],
                        fmaf(xn1, Wr[1*HDIM + c],
                        fmaf(xn2, Wr[2*HDIM + c], br[c])));
            hA[k0 + c][lane] = sinf(W0F * pre);
        }
    }
    __syncthreads();

    // ---- hidden layers (j-phased for K$ residency) ----
    for (int l = 0; l < NDEPTH; ++l) {
        const float* Wl = W_h + ((size_t)(r * NDEPTH + l)) * HDIM * HDIM + k0;
        const float* bl = b_h + (r * NDEPTH + l) * HDIM + k0;
        float acc[16];
        #pragma unroll
        for (int c = 0; c < 16; ++c) acc[c] = bl[c];   // bias-init (scalar load)

        for (int ph = 0; ph < 4; ++ph) {               // 4 x 32-j phases, 16KB window
            const int j0 = ph * 32;
            #pragma unroll 4
            for (int j = j0; j < j0 + 32; ++j) {
                float a = hA[j][lane];                  // 1 ds_read_b32 / wave / j
                const float* wrow = Wl + (size_t)j * HDIM;  // uniform row -> s_load_x16
                #pragma unroll
                for (int c = 0; c < 16; ++c)
                    acc[c] = fmaf(wrow[c], a, acc[c]);  // v_fmac with SGPR weight
            }
            __syncthreads();   // keep all waves inside the same K$ window
        }
        // (the ph=3 barrier doubles as the "all reads done" barrier)

        // sin in registers, then in-place overwrite of hA
        #pragma unroll
        for (int c = 0; c < 16; ++c) acc[c] = sinf(W0F * acc[c]);
        #pragma unroll
        for (int c = 0; c < 16; ++c) hA[k0 + c][lane] = acc[c];
        __syncthreads();   // writes visible before next layer reads
    }

    // ---- output layer: partial dot per 16-ch chunk, reduce via LDS ----
    {
        const float* Wo = W_out + r * HDIM + k0;       // uniform -> s_load
        float s = 0.f;
        #pragma unroll
        for (int c = 0; c < 16; ++c)
            s = fmaf(Wo[c], hA[k0 + c][lane], s);
        part[wv][lane] = s;
    }
    __syncthreads();
    if (wv == 0) {
        float s = part[0][lane] + part[1][lane] + part[2][lane] + part[3][lane]
                + part[4][lane] + part[5][lane] + part[6][lane] + part[7][lane]
                + b_out[r];
        if (g >= 0) out[g] = s;
    }
}

// ---------------- launcher ----------------

extern "C" void kernel_launch(void* const* d_in, const int* in_sizes, int n_in,
                              void* d_out, int out_size, void* d_ws, size_t ws_size,
                              hipStream_t stream) {
    const float* x      = (const float*)d_in[0];
    const float* W_in   = (const float*)d_in[1];
    const float* b_in   = (const float*)d_in[2];
    const float* W_h    = (const float*)d_in[3];
    const float* b_h    = (const float*)d_in[4];
    const float* W_out  = (const float*)d_in[5];
    const float* b_out  = (const float*)d_in[6];
    const float* scale  = (const float*)d_in[7];
    const float* boxes  = (const float*)d_in[8];
    float* out = (float*)d_out;

    int n = in_sizes[0] / 3;
    int* wsi = (int*)d_ws;
    int* idx = (int*)((char*)d_ws + 256);

    hipMemsetAsync(d_ws, 0, 256, stream);

    int nb = (n + 255) / 256;
    hipLaunchKernelGGL(k_count,   dim3(nb), dim3(256), 0, stream, x, n, wsi);
    hipLaunchKernelGGL(k_prefix,  dim3(1),  dim3(64),  0, stream, wsi);
    hipLaunchKernelGGL(k_scatter, dim3(nb), dim3(256), 0, stream, x, n, wsi, idx, out);

    int ntiles = (n + TP - 1) / TP + NREG;
    hipLaunchKernelGGL(k_mlp, dim3(ntiles), dim3(512), 0, stream,
                       x, W_in, b_in, W_h, b_h, W_out, b_out, scale, boxes,
                       wsi + 8, idx, out);
}